// Round 3
// baseline (964.473 us; speedup 1.0000x reference)
//
#include <hip/hip_runtime.h>

#define CDIM 64
#define KCODES 1024
#define ZQ_ELEMS (32 * 64 * 64 * 64)  // 8388608
#define FLT_BIG 3.402823466e38f
#define NBLK 2048                     // 131072 rows / 64 rows per block

// Block = 64 rows x 4 k-segments (wave w scans codes [w*256, w*256+256)).
// Exact numpy fp32 semantics: A,B via 8-acc pairwise sum; M via sequential fma
// in ascending c; d = fl(fl(A+B)-2M); argmin strict < ascending k.

#define LOADZ(i) \
    float4 Z##i = make_float4(zp[(4 * i + 0) << 12], zp[(4 * i + 1) << 12], \
                              zp[(4 * i + 2) << 12], zp[(4 * i + 3) << 12]);

#define ASTEP(Za, Zb) \
    r0 = __fadd_rn(r0, __fmul_rn(Za.x, Za.x)); \
    r1 = __fadd_rn(r1, __fmul_rn(Za.y, Za.y)); \
    r2 = __fadd_rn(r2, __fmul_rn(Za.z, Za.z)); \
    r3 = __fadd_rn(r3, __fmul_rn(Za.w, Za.w)); \
    r4 = __fadd_rn(r4, __fmul_rn(Zb.x, Zb.x)); \
    r5 = __fadd_rn(r5, __fmul_rn(Zb.y, Zb.y)); \
    r6 = __fadd_rn(r6, __fmul_rn(Zb.z, Zb.z)); \
    r7 = __fadd_rn(r7, __fmul_rn(Zb.w, Zb.w));

#define KSTEP(Zq, q) \
    { \
        float4 e0 = C0[q], e1 = C1[q], e2 = C2[q], e3 = C3[q]; \
        m0 = __fmaf_rn(Zq.x, e0.x, m0); \
        m0 = __fmaf_rn(Zq.y, e0.y, m0); \
        m0 = __fmaf_rn(Zq.z, e0.z, m0); \
        m0 = __fmaf_rn(Zq.w, e0.w, m0); \
        m1 = __fmaf_rn(Zq.x, e1.x, m1); \
        m1 = __fmaf_rn(Zq.y, e1.y, m1); \
        m1 = __fmaf_rn(Zq.z, e1.z, m1); \
        m1 = __fmaf_rn(Zq.w, e1.w, m1); \
        m2 = __fmaf_rn(Zq.x, e2.x, m2); \
        m2 = __fmaf_rn(Zq.y, e2.y, m2); \
        m2 = __fmaf_rn(Zq.z, e2.z, m2); \
        m2 = __fmaf_rn(Zq.w, e2.w, m2); \
        m3 = __fmaf_rn(Zq.x, e3.x, m3); \
        m3 = __fmaf_rn(Zq.y, e3.y, m3); \
        m3 = __fmaf_rn(Zq.z, e3.z, m3); \
        m3 = __fmaf_rn(Zq.w, e3.w, m3); \
    }

#define LSTEP(i, Zi) \
    { \
        float4 qv = cq4[i]; \
        zo[(4 * i + 0) << 12] = qv.x; \
        zo[(4 * i + 1) << 12] = qv.y; \
        zo[(4 * i + 2) << 12] = qv.z; \
        zo[(4 * i + 3) << 12] = qv.w; \
        lsum = fmaf(qv.x - Zi.x, qv.x - Zi.x, lsum); \
        lsum = fmaf(qv.y - Zi.y, qv.y - Zi.y, lsum); \
        lsum = fmaf(qv.z - Zi.z, qv.z - Zi.z, lsum); \
        lsum = fmaf(qv.w - Zi.w, qv.w - Zi.w, lsum); \
    }

__global__ __launch_bounds__(256, 4) void vq_main(const float* __restrict__ z,
                                                  const float* __restrict__ cb,
                                                  float* __restrict__ zq_out,
                                                  float* __restrict__ idx_out,
                                                  double* __restrict__ part) {
    __shared__ float sB[KCODES];
    __shared__ float sD[256];
    __shared__ int sI[256];
    const int tid = threadIdx.x;

    // B_k, numpy 8-acc pairwise (4 codes per thread; cold code)
    for (int k = tid; k < KCODES; k += 256) {
        const float* ck = cb + k * CDIM;
        float r[8];
        #pragma unroll
        for (int j = 0; j < 8; ++j) r[j] = __fmul_rn(ck[j], ck[j]);
        #pragma unroll
        for (int m = 1; m < 8; ++m) {
            #pragma unroll
            for (int j = 0; j < 8; ++j)
                r[j] = __fadd_rn(r[j], __fmul_rn(ck[8 * m + j], ck[8 * m + j]));
        }
        sB[k] = __fadd_rn(__fadd_rn(__fadd_rn(r[0], r[1]), __fadd_rn(r[2], r[3])),
                          __fadd_rn(__fadd_rn(r[4], r[5]), __fadd_rn(r[6], r[7])));
    }
    __syncthreads();

    const int lane = tid & 63;                  // row within block
    const int kseg = tid >> 6;                  // wave -> k segment
    const int n = blockIdx.x * 64 + lane;       // row id
    const int b = n >> 12;
    const int hw = n & 4095;
    const float* __restrict__ zp = z + ((size_t)b << 18) + hw;

    LOADZ(0)  LOADZ(1)  LOADZ(2)  LOADZ(3)
    LOADZ(4)  LOADZ(5)  LOADZ(6)  LOADZ(7)
    LOADZ(8)  LOADZ(9)  LOADZ(10) LOADZ(11)
    LOADZ(12) LOADZ(13) LOADZ(14) LOADZ(15)

    // A, numpy pairwise
    float r0 = __fmul_rn(Z0.x, Z0.x), r1 = __fmul_rn(Z0.y, Z0.y);
    float r2 = __fmul_rn(Z0.z, Z0.z), r3 = __fmul_rn(Z0.w, Z0.w);
    float r4 = __fmul_rn(Z1.x, Z1.x), r5 = __fmul_rn(Z1.y, Z1.y);
    float r6 = __fmul_rn(Z1.z, Z1.z), r7 = __fmul_rn(Z1.w, Z1.w);
    ASTEP(Z2, Z3)   ASTEP(Z4, Z5)   ASTEP(Z6, Z7)
    ASTEP(Z8, Z9)   ASTEP(Z10, Z11) ASTEP(Z12, Z13) ASTEP(Z14, Z15)
    const float A = __fadd_rn(__fadd_rn(__fadd_rn(r0, r1), __fadd_rn(r2, r3)),
                              __fadd_rn(__fadd_rn(r4, r5), __fadd_rn(r6, r7)));

    float best = FLT_BIG;
    int bi = 0;
    const int kbase = kseg << 8;               // 256 codes per wave

    for (int k = kbase; k < kbase + 256; k += 4) {
        const float4* __restrict__ C0 = (const float4*)(cb + (size_t)(k + 0) * CDIM);
        const float4* __restrict__ C1 = (const float4*)(cb + (size_t)(k + 1) * CDIM);
        const float4* __restrict__ C2 = (const float4*)(cb + (size_t)(k + 2) * CDIM);
        const float4* __restrict__ C3 = (const float4*)(cb + (size_t)(k + 3) * CDIM);
        float m0 = 0.f, m1 = 0.f, m2 = 0.f, m3 = 0.f;
        KSTEP(Z0, 0)   KSTEP(Z1, 1)   KSTEP(Z2, 2)   KSTEP(Z3, 3)
        KSTEP(Z4, 4)   KSTEP(Z5, 5)   KSTEP(Z6, 6)   KSTEP(Z7, 7)
        KSTEP(Z8, 8)   KSTEP(Z9, 9)   KSTEP(Z10, 10) KSTEP(Z11, 11)
        KSTEP(Z12, 12) KSTEP(Z13, 13) KSTEP(Z14, 14) KSTEP(Z15, 15)

        float4 B4 = ((const float4*)sB)[k >> 2];    // one ds_read_b128, uniform
        float d0 = __fsub_rn(__fadd_rn(A, B4.x), __fadd_rn(m0, m0));
        float d1 = __fsub_rn(__fadd_rn(A, B4.y), __fadd_rn(m1, m1));
        float d2 = __fsub_rn(__fadd_rn(A, B4.z), __fadd_rn(m2, m2));
        float d3 = __fsub_rn(__fadd_rn(A, B4.w), __fadd_rn(m3, m3));
        if (d0 < best) { best = d0; bi = k + 0; }
        if (d1 < best) { best = d1; bi = k + 1; }
        if (d2 < best) { best = d2; bi = k + 2; }
        if (d3 < best) { best = d3; bi = k + 3; }
    }

    sD[tid] = best;
    sI[tid] = bi;
    __syncthreads();

    if (tid < 64) {
        // combine segments in ascending-k order; strict < keeps first index
        float bd = sD[tid];
        int bk = sI[tid];
        #pragma unroll
        for (int s = 1; s < 4; ++s) {
            float d = sD[s * 64 + tid];
            int kk = sI[s * 64 + tid];
            if (d < bd) { bd = d; bk = kk; }
        }

        idx_out[n] = (float)bk;

        const float4* __restrict__ cq4 = (const float4*)(cb + (size_t)bk * CDIM);
        float* __restrict__ zo = zq_out + ((size_t)b << 18) + hw;
        float lsum = 0.f;
        LSTEP(0, Z0)   LSTEP(1, Z1)   LSTEP(2, Z2)   LSTEP(3, Z3)
        LSTEP(4, Z4)   LSTEP(5, Z5)   LSTEP(6, Z6)   LSTEP(7, Z7)
        LSTEP(8, Z8)   LSTEP(9, Z9)   LSTEP(10, Z10) LSTEP(11, Z11)
        LSTEP(12, Z12) LSTEP(13, Z13) LSTEP(14, Z14) LSTEP(15, Z15)

        double ls = (double)lsum;
        for (int off = 32; off > 0; off >>= 1) ls += __shfl_down(ls, off, 64);
        if (tid == 0) part[blockIdx.x] = ls;
    }
}

__global__ void vq_finalize(const double* __restrict__ part, float* __restrict__ loss_out) {
    __shared__ double s[16];
    const int tid = threadIdx.x;       // 1024 threads, one block
    double v = part[tid] + part[tid + 1024];
    for (int off = 32; off > 0; off >>= 1) v += __shfl_down(v, off, 64);
    if ((tid & 63) == 0) s[tid >> 6] = v;
    __syncthreads();
    if (tid == 0) {
        double t = 0.0;
        #pragma unroll
        for (int i = 0; i < 16; ++i) t += s[i];
        // loss = codebook_loss + 0.25*commitment = 1.25 * mean((z_q - z)^2)
        *loss_out = (float)(1.25 * t / (double)ZQ_ELEMS);
    }
}

extern "C" void kernel_launch(void* const* d_in, const int* in_sizes, int n_in,
                              void* d_out, int out_size, void* d_ws, size_t ws_size,
                              hipStream_t stream) {
    const float* z  = (const float*)d_in[0];
    const float* cb = (const float*)d_in[1];
    float* out  = (float*)d_out;
    float* zq   = out;                       // 8388608
    float* loss = out + ZQ_ELEMS;            // 1
    float* idx  = out + ZQ_ELEMS + 1;        // 131072
    double* part = (double*)d_ws;            // 2048 doubles

    vq_main<<<NBLK, 256, 0, stream>>>(z, cb, zq, idx, part);
    vq_finalize<<<1, 1024, 0, stream>>>(part, loss);
}

// Round 4
// 347.200 us; speedup vs baseline: 2.7779x; 2.7779x over previous
//
#include <hip/hip_runtime.h>

#define CDIM 64
#define KCODES 1024
#define ZQ_ELEMS (32 * 64 * 64 * 64)  // 8388608
#define FLT_BIG 3.402823466e38f
#define NBLK 2048                     // 131072 rows / 64 rows per block

// Block = 64 rows x 4 k-segments; wave w scans codes [w*256, w*256+256) with a
// readfirstlane'd (SGPR) base so codebook loads scalarize (s_load path).
// z row pinned in VGPRs via named float4 + asm remat-barrier.
// Exact numpy fp32 semantics: A,B via 8-acc pairwise sum; M via sequential fma
// in ascending c; d = fl(fl(A+B)-2M); argmin strict < ascending k.

#define LOADZ(i) \
    float4 Z##i = make_float4(zp[(4 * i + 0) << 12], zp[(4 * i + 1) << 12], \
                              zp[(4 * i + 2) << 12], zp[(4 * i + 3) << 12]); \
    asm volatile("" : "+v"(Z##i.x), "+v"(Z##i.y), "+v"(Z##i.z), "+v"(Z##i.w));

#define ASTEP(Za, Zb) \
    r0 = __fadd_rn(r0, __fmul_rn(Za.x, Za.x)); \
    r1 = __fadd_rn(r1, __fmul_rn(Za.y, Za.y)); \
    r2 = __fadd_rn(r2, __fmul_rn(Za.z, Za.z)); \
    r3 = __fadd_rn(r3, __fmul_rn(Za.w, Za.w)); \
    r4 = __fadd_rn(r4, __fmul_rn(Zb.x, Zb.x)); \
    r5 = __fadd_rn(r5, __fmul_rn(Zb.y, Zb.y)); \
    r6 = __fadd_rn(r6, __fmul_rn(Zb.z, Zb.z)); \
    r7 = __fadd_rn(r7, __fmul_rn(Zb.w, Zb.w));

#define KSTEP(Zq, q) \
    { \
        float4 e0 = C0[q], e1 = C1[q], e2 = C2[q], e3 = C3[q]; \
        m0 = __fmaf_rn(Zq.x, e0.x, m0); \
        m0 = __fmaf_rn(Zq.y, e0.y, m0); \
        m0 = __fmaf_rn(Zq.z, e0.z, m0); \
        m0 = __fmaf_rn(Zq.w, e0.w, m0); \
        m1 = __fmaf_rn(Zq.x, e1.x, m1); \
        m1 = __fmaf_rn(Zq.y, e1.y, m1); \
        m1 = __fmaf_rn(Zq.z, e1.z, m1); \
        m1 = __fmaf_rn(Zq.w, e1.w, m1); \
        m2 = __fmaf_rn(Zq.x, e2.x, m2); \
        m2 = __fmaf_rn(Zq.y, e2.y, m2); \
        m2 = __fmaf_rn(Zq.z, e2.z, m2); \
        m2 = __fmaf_rn(Zq.w, e2.w, m2); \
        m3 = __fmaf_rn(Zq.x, e3.x, m3); \
        m3 = __fmaf_rn(Zq.y, e3.y, m3); \
        m3 = __fmaf_rn(Zq.z, e3.z, m3); \
        m3 = __fmaf_rn(Zq.w, e3.w, m3); \
    }

#define LSTEP(i, Zi) \
    { \
        float4 qv = cq4[i]; \
        zo[(4 * i + 0) << 12] = qv.x; \
        zo[(4 * i + 1) << 12] = qv.y; \
        zo[(4 * i + 2) << 12] = qv.z; \
        zo[(4 * i + 3) << 12] = qv.w; \
        lsum = fmaf(qv.x - Zi.x, qv.x - Zi.x, lsum); \
        lsum = fmaf(qv.y - Zi.y, qv.y - Zi.y, lsum); \
        lsum = fmaf(qv.z - Zi.z, qv.z - Zi.z, lsum); \
        lsum = fmaf(qv.w - Zi.w, qv.w - Zi.w, lsum); \
    }

__global__ __launch_bounds__(256, 4) void vq_main(const float* __restrict__ z,
                                                  const float* __restrict__ cb,
                                                  float* __restrict__ zq_out,
                                                  float* __restrict__ idx_out,
                                                  double* __restrict__ part) {
    __shared__ float sB[KCODES];
    __shared__ float sD[256];
    __shared__ int sI[256];
    const int tid = threadIdx.x;

    // B_k, numpy 8-acc pairwise (4 codes per thread; cold code)
    for (int k = tid; k < KCODES; k += 256) {
        const float* ck = cb + k * CDIM;
        float r[8];
        #pragma unroll
        for (int j = 0; j < 8; ++j) r[j] = __fmul_rn(ck[j], ck[j]);
        #pragma unroll
        for (int m = 1; m < 8; ++m) {
            #pragma unroll
            for (int j = 0; j < 8; ++j)
                r[j] = __fadd_rn(r[j], __fmul_rn(ck[8 * m + j], ck[8 * m + j]));
        }
        sB[k] = __fadd_rn(__fadd_rn(__fadd_rn(r[0], r[1]), __fadd_rn(r[2], r[3])),
                          __fadd_rn(__fadd_rn(r[4], r[5]), __fadd_rn(r[6], r[7])));
    }
    __syncthreads();

    const int lane = tid & 63;                  // row within block
    const int kseg = tid >> 6;                  // wave -> k segment
    const int n = blockIdx.x * 64 + lane;       // row id
    const int b = n >> 12;
    const int hw = n & 4095;
    const float* __restrict__ zp = z + ((size_t)b << 18) + hw;

    LOADZ(0)  LOADZ(1)  LOADZ(2)  LOADZ(3)
    LOADZ(4)  LOADZ(5)  LOADZ(6)  LOADZ(7)
    LOADZ(8)  LOADZ(9)  LOADZ(10) LOADZ(11)
    LOADZ(12) LOADZ(13) LOADZ(14) LOADZ(15)

    // A, numpy pairwise
    float r0 = __fmul_rn(Z0.x, Z0.x), r1 = __fmul_rn(Z0.y, Z0.y);
    float r2 = __fmul_rn(Z0.z, Z0.z), r3 = __fmul_rn(Z0.w, Z0.w);
    float r4 = __fmul_rn(Z1.x, Z1.x), r5 = __fmul_rn(Z1.y, Z1.y);
    float r6 = __fmul_rn(Z1.z, Z1.z), r7 = __fmul_rn(Z1.w, Z1.w);
    ASTEP(Z2, Z3)   ASTEP(Z4, Z5)   ASTEP(Z6, Z7)
    ASTEP(Z8, Z9)   ASTEP(Z10, Z11) ASTEP(Z12, Z13) ASTEP(Z14, Z15)
    const float A = __fadd_rn(__fadd_rn(__fadd_rn(r0, r1), __fadd_rn(r2, r3)),
                              __fadd_rn(__fadd_rn(r4, r5), __fadd_rn(r6, r7)));

    float best = FLT_BIG;
    int bi = 0;
    // SGPR segment base -> provably uniform codebook addresses -> s_load path
    const int kbase = __builtin_amdgcn_readfirstlane(kseg << 8);

    for (int k = kbase; k < kbase + 256; k += 4) {
        const float4* __restrict__ C0 = (const float4*)(cb + (size_t)(k + 0) * CDIM);
        const float4* __restrict__ C1 = (const float4*)(cb + (size_t)(k + 1) * CDIM);
        const float4* __restrict__ C2 = (const float4*)(cb + (size_t)(k + 2) * CDIM);
        const float4* __restrict__ C3 = (const float4*)(cb + (size_t)(k + 3) * CDIM);
        float m0 = 0.f, m1 = 0.f, m2 = 0.f, m3 = 0.f;
        KSTEP(Z0, 0)   KSTEP(Z1, 1)   KSTEP(Z2, 2)   KSTEP(Z3, 3)
        KSTEP(Z4, 4)   KSTEP(Z5, 5)   KSTEP(Z6, 6)   KSTEP(Z7, 7)
        KSTEP(Z8, 8)   KSTEP(Z9, 9)   KSTEP(Z10, 10) KSTEP(Z11, 11)
        KSTEP(Z12, 12) KSTEP(Z13, 13) KSTEP(Z14, 14) KSTEP(Z15, 15)

        float4 B4 = ((const float4*)sB)[k >> 2];
        float d0 = __fsub_rn(__fadd_rn(A, B4.x), __fadd_rn(m0, m0));
        float d1 = __fsub_rn(__fadd_rn(A, B4.y), __fadd_rn(m1, m1));
        float d2 = __fsub_rn(__fadd_rn(A, B4.z), __fadd_rn(m2, m2));
        float d3 = __fsub_rn(__fadd_rn(A, B4.w), __fadd_rn(m3, m3));
        if (d0 < best) { best = d0; bi = k + 0; }
        if (d1 < best) { best = d1; bi = k + 1; }
        if (d2 < best) { best = d2; bi = k + 2; }
        if (d3 < best) { best = d3; bi = k + 3; }
    }

    sD[tid] = best;
    sI[tid] = bi;
    __syncthreads();

    if (tid < 64) {
        // combine segments in ascending-k order; strict < keeps first index
        float bd = sD[tid];
        int bk = sI[tid];
        #pragma unroll
        for (int s = 1; s < 4; ++s) {
            float d = sD[s * 64 + tid];
            int kk = sI[s * 64 + tid];
            if (d < bd) { bd = d; bk = kk; }
        }

        idx_out[n] = (float)bk;

        const float4* __restrict__ cq4 = (const float4*)(cb + (size_t)bk * CDIM);
        float* __restrict__ zo = zq_out + ((size_t)b << 18) + hw;
        float lsum = 0.f;
        LSTEP(0, Z0)   LSTEP(1, Z1)   LSTEP(2, Z2)   LSTEP(3, Z3)
        LSTEP(4, Z4)   LSTEP(5, Z5)   LSTEP(6, Z6)   LSTEP(7, Z7)
        LSTEP(8, Z8)   LSTEP(9, Z9)   LSTEP(10, Z10) LSTEP(11, Z11)
        LSTEP(12, Z12) LSTEP(13, Z13) LSTEP(14, Z14) LSTEP(15, Z15)

        double ls = (double)lsum;
        for (int off = 32; off > 0; off >>= 1) ls += __shfl_down(ls, off, 64);
        if (tid == 0) part[blockIdx.x] = ls;
    }
}

__global__ void vq_finalize(const double* __restrict__ part, float* __restrict__ loss_out) {
    __shared__ double s[16];
    const int tid = threadIdx.x;       // 1024 threads, one block
    double v = part[tid] + part[tid + 1024];
    for (int off = 32; off > 0; off >>= 1) v += __shfl_down(v, off, 64);
    if ((tid & 63) == 0) s[tid >> 6] = v;
    __syncthreads();
    if (tid == 0) {
        double t = 0.0;
        #pragma unroll
        for (int i = 0; i < 16; ++i) t += s[i];
        // loss = codebook_loss + 0.25*commitment = 1.25 * mean((z_q - z)^2)
        *loss_out = (float)(1.25 * t / (double)ZQ_ELEMS);
    }
}

extern "C" void kernel_launch(void* const* d_in, const int* in_sizes, int n_in,
                              void* d_out, int out_size, void* d_ws, size_t ws_size,
                              hipStream_t stream) {
    const float* z  = (const float*)d_in[0];
    const float* cb = (const float*)d_in[1];
    float* out  = (float*)d_out;
    float* zq   = out;                       // 8388608
    float* loss = out + ZQ_ELEMS;            // 1
    float* idx  = out + ZQ_ELEMS + 1;        // 131072
    double* part = (double*)d_ws;            // 2048 doubles

    vq_main<<<NBLK, 256, 0, stream>>>(z, cb, zq, idx, part);
    vq_finalize<<<1, 1024, 0, stream>>>(part, loss);
}

// Round 5
// 309.970 us; speedup vs baseline: 3.1115x; 1.1201x over previous
//
#include <hip/hip_runtime.h>

#define CDIM 64
#define KCODES 1024
#define ZQ_ELEMS (32 * 64 * 64 * 64)  // 8388608
#define NROWS 131072
#define FLT_BIG 3.402823466e38f
#define NBLK 2048                     // 131072 rows / 64 rows per block

// ws layout (fast path): [0,16KB) part | [16KB,20KB) Bsq | [32KB, +32MB) zt
#define WS_BSQ_OFF   16384
#define WS_ZT_OFF    32768
#define WS_NEEDED    (WS_ZT_OFF + (size_t)NROWS * CDIM * 4)

// ---------------- numpy-exact helpers ----------------
// B_k / A: numpy 8-accumulator pairwise sum of squares over 64 elements.
// M: strictly sequential fma over c (BLAS sgemm microkernel order).
// d = fl(fl(A+B) - 2M); argmin strict < in ascending k.

__device__ __forceinline__ float pairwise_sq64(const float* v) {
    float r[8];
    #pragma unroll
    for (int j = 0; j < 8; ++j) r[j] = __fmul_rn(v[j], v[j]);
    #pragma unroll
    for (int m = 1; m < 8; ++m) {
        #pragma unroll
        for (int j = 0; j < 8; ++j)
            r[j] = __fadd_rn(r[j], __fmul_rn(v[8 * m + j], v[8 * m + j]));
    }
    return __fadd_rn(__fadd_rn(__fadd_rn(r[0], r[1]), __fadd_rn(r[2], r[3])),
                     __fadd_rn(__fadd_rn(r[4], r[5]), __fadd_rn(r[6], r[7])));
}

// ---------------- prep: transpose z -> zt (contig rows) + Bsq ----------------
__global__ __launch_bounds__(256) void vq_prep(const float* __restrict__ z,
                                               const float* __restrict__ cb,
                                               float* __restrict__ zt,
                                               float* __restrict__ Bsq) {
    __shared__ float tile[64][65];
    const int tid = threadIdx.x;
    const int blk = blockIdx.x;
    const int n0 = blk * 64;
    const int b = n0 >> 12;
    const int hw0 = n0 & 4095;
    const float* __restrict__ zb = z + ((size_t)b << 18) + hw0;

    const int lane_hw = tid & 63;
    const int cg = tid >> 6;
    #pragma unroll
    for (int it = 0; it < 16; ++it) {
        int c = cg * 16 + it;
        tile[lane_hw][c] = zb[((size_t)c << 12) + lane_hw];   // coalesced read
    }
    __syncthreads();

    const int r = tid >> 2;
    const int cq = tid & 3;
    float4* __restrict__ zrow = (float4*)(zt + (size_t)(n0 + r) * CDIM);
    #pragma unroll
    for (int q = 0; q < 4; ++q) {
        int c0 = cq * 16 + q * 4;
        float4 v = make_float4(tile[r][c0], tile[r][c0 + 1], tile[r][c0 + 2], tile[r][c0 + 3]);
        zrow[c0 >> 2] = v;                                    // coalesced write
    }

    if (blk < 4) {                       // Bsq: 4 blocks x 256 threads = 1024 codes
        int k = blk * 256 + tid;
        Bsq[k] = pairwise_sq64(cb + k * CDIM);
    }
}

// ---------------- main ----------------
#define LOADZ_STRIDED(i) \
    float4 Z##i = make_float4(zp[(4 * i + 0) << 12], zp[(4 * i + 1) << 12], \
                              zp[(4 * i + 2) << 12], zp[(4 * i + 3) << 12]); \
    asm volatile("" : "+v"(Z##i.x), "+v"(Z##i.y), "+v"(Z##i.z), "+v"(Z##i.w));

#define KSTEP(Zq, q) \
    { \
        float4 e0 = C0[q], e1 = C1[q], e2 = C2[q], e3 = C3[q]; \
        m0 = __fmaf_rn(Zq.x, e0.x, m0); \
        m0 = __fmaf_rn(Zq.y, e0.y, m0); \
        m0 = __fmaf_rn(Zq.z, e0.z, m0); \
        m0 = __fmaf_rn(Zq.w, e0.w, m0); \
        m1 = __fmaf_rn(Zq.x, e1.x, m1); \
        m1 = __fmaf_rn(Zq.y, e1.y, m1); \
        m1 = __fmaf_rn(Zq.z, e1.z, m1); \
        m1 = __fmaf_rn(Zq.w, e1.w, m1); \
        m2 = __fmaf_rn(Zq.x, e2.x, m2); \
        m2 = __fmaf_rn(Zq.y, e2.y, m2); \
        m2 = __fmaf_rn(Zq.z, e2.z, m2); \
        m2 = __fmaf_rn(Zq.w, e2.w, m2); \
        m3 = __fmaf_rn(Zq.x, e3.x, m3); \
        m3 = __fmaf_rn(Zq.y, e3.y, m3); \
        m3 = __fmaf_rn(Zq.z, e3.z, m3); \
        m3 = __fmaf_rn(Zq.w, e3.w, m3); \
    }

#define LSTEP(i, Zi) \
    { \
        float4 qv = cq4[i]; \
        zo[(4 * i + 0) << 12] = qv.x; \
        zo[(4 * i + 1) << 12] = qv.y; \
        zo[(4 * i + 2) << 12] = qv.z; \
        zo[(4 * i + 3) << 12] = qv.w; \
        lsum = fmaf(qv.x - Zi.x, qv.x - Zi.x, lsum); \
        lsum = fmaf(qv.y - Zi.y, qv.y - Zi.y, lsum); \
        lsum = fmaf(qv.z - Zi.z, qv.z - Zi.z, lsum); \
        lsum = fmaf(qv.w - Zi.w, qv.w - Zi.w, lsum); \
    }

template <bool CONTIG>
__global__ __launch_bounds__(256, 4) void vq_main(const float* __restrict__ z,
                                                  const float* __restrict__ cb,
                                                  const float* __restrict__ Bsq,
                                                  float* __restrict__ zq_out,
                                                  float* __restrict__ idx_out,
                                                  double* __restrict__ part) {
    __shared__ float sB[KCODES];
    __shared__ float sD[256];
    __shared__ int sI[256];
    const int tid = threadIdx.x;

    if constexpr (CONTIG) {
        #pragma unroll
        for (int k = tid; k < KCODES; k += 256) sB[k] = Bsq[k];
    } else {
        for (int k = tid; k < KCODES; k += 256) sB[k] = pairwise_sq64(cb + k * CDIM);
    }
    __syncthreads();

    const int lane = tid & 63;                  // row within block
    const int kseg = tid >> 6;                  // wave -> k segment
    const int n = blockIdx.x * 64 + lane;       // row id
    const int b = n >> 12;
    const int hw = n & 4095;

    float4 Z0, Z1, Z2, Z3, Z4, Z5, Z6, Z7, Z8, Z9, Z10, Z11, Z12, Z13, Z14, Z15;
    if constexpr (CONTIG) {
        const float4* __restrict__ zr = (const float4*)(z + (size_t)n * CDIM);
        Z0 = zr[0];   Z1 = zr[1];   Z2 = zr[2];   Z3 = zr[3];
        Z4 = zr[4];   Z5 = zr[5];   Z6 = zr[6];   Z7 = zr[7];
        Z8 = zr[8];   Z9 = zr[9];   Z10 = zr[10]; Z11 = zr[11];
        Z12 = zr[12]; Z13 = zr[13]; Z14 = zr[14]; Z15 = zr[15];
    } else {
        const float* __restrict__ zp = z + ((size_t)b << 18) + hw;
        LOADZ_STRIDED(0)  LOADZ_STRIDED(1)  LOADZ_STRIDED(2)  LOADZ_STRIDED(3)
        LOADZ_STRIDED(4)  LOADZ_STRIDED(5)  LOADZ_STRIDED(6)  LOADZ_STRIDED(7)
        LOADZ_STRIDED(8)  LOADZ_STRIDED(9)  LOADZ_STRIDED(10) LOADZ_STRIDED(11)
        LOADZ_STRIDED(12) LOADZ_STRIDED(13) LOADZ_STRIDED(14) LOADZ_STRIDED(15)
        // silence unused warnings for the copies below
        (void)zp;
    }

    // A, numpy pairwise (8-acc over the 16 float4s)
    float zarr[CDIM];
    #pragma unroll
    for (int i = 0; i < 16; ++i) {
        const float4 Zi = (i == 0 ? Z0 : i == 1 ? Z1 : i == 2 ? Z2 : i == 3 ? Z3 :
                           i == 4 ? Z4 : i == 5 ? Z5 : i == 6 ? Z6 : i == 7 ? Z7 :
                           i == 8 ? Z8 : i == 9 ? Z9 : i == 10 ? Z10 : i == 11 ? Z11 :
                           i == 12 ? Z12 : i == 13 ? Z13 : i == 14 ? Z14 : Z15);
        zarr[4 * i + 0] = Zi.x; zarr[4 * i + 1] = Zi.y;
        zarr[4 * i + 2] = Zi.z; zarr[4 * i + 3] = Zi.w;
    }
    const float A = pairwise_sq64(zarr);

    float best = FLT_BIG;
    int bi = 0;
    // SGPR segment base -> provably uniform codebook addresses -> s_load path
    const int kbase = __builtin_amdgcn_readfirstlane(kseg << 8);

    for (int k = kbase; k < kbase + 256; k += 4) {
        const float4* __restrict__ C0 = (const float4*)(cb + (size_t)(k + 0) * CDIM);
        const float4* __restrict__ C1 = (const float4*)(cb + (size_t)(k + 1) * CDIM);
        const float4* __restrict__ C2 = (const float4*)(cb + (size_t)(k + 2) * CDIM);
        const float4* __restrict__ C3 = (const float4*)(cb + (size_t)(k + 3) * CDIM);
        float m0 = 0.f, m1 = 0.f, m2 = 0.f, m3 = 0.f;
        KSTEP(Z0, 0)   KSTEP(Z1, 1)   KSTEP(Z2, 2)   KSTEP(Z3, 3)
        KSTEP(Z4, 4)   KSTEP(Z5, 5)   KSTEP(Z6, 6)   KSTEP(Z7, 7)
        KSTEP(Z8, 8)   KSTEP(Z9, 9)   KSTEP(Z10, 10) KSTEP(Z11, 11)
        KSTEP(Z12, 12) KSTEP(Z13, 13) KSTEP(Z14, 14) KSTEP(Z15, 15)

        float4 B4 = ((const float4*)sB)[k >> 2];
        float d0 = __fsub_rn(__fadd_rn(A, B4.x), __fadd_rn(m0, m0));
        float d1 = __fsub_rn(__fadd_rn(A, B4.y), __fadd_rn(m1, m1));
        float d2 = __fsub_rn(__fadd_rn(A, B4.z), __fadd_rn(m2, m2));
        float d3 = __fsub_rn(__fadd_rn(A, B4.w), __fadd_rn(m3, m3));
        if (d0 < best) { best = d0; bi = k + 0; }
        if (d1 < best) { best = d1; bi = k + 1; }
        if (d2 < best) { best = d2; bi = k + 2; }
        if (d3 < best) { best = d3; bi = k + 3; }
    }

    sD[tid] = best;
    sI[tid] = bi;
    __syncthreads();

    if (tid < 64) {
        // combine segments in ascending-k order; strict < keeps first index
        float bd = sD[tid];
        int bk = sI[tid];
        #pragma unroll
        for (int s = 1; s < 4; ++s) {
            float d = sD[s * 64 + tid];
            int kk = sI[s * 64 + tid];
            if (d < bd) { bd = d; bk = kk; }
        }

        idx_out[n] = (float)bk;

        const float4* __restrict__ cq4 = (const float4*)(cb + (size_t)bk * CDIM);
        float* __restrict__ zo = zq_out + ((size_t)b << 18) + hw;
        float lsum = 0.f;
        LSTEP(0, Z0)   LSTEP(1, Z1)   LSTEP(2, Z2)   LSTEP(3, Z3)
        LSTEP(4, Z4)   LSTEP(5, Z5)   LSTEP(6, Z6)   LSTEP(7, Z7)
        LSTEP(8, Z8)   LSTEP(9, Z9)   LSTEP(10, Z10) LSTEP(11, Z11)
        LSTEP(12, Z12) LSTEP(13, Z13) LSTEP(14, Z14) LSTEP(15, Z15)

        double ls = (double)lsum;
        for (int off = 32; off > 0; off >>= 1) ls += __shfl_down(ls, off, 64);
        if (tid == 0) part[blockIdx.x] = ls;
    }
}

__global__ void vq_finalize(const double* __restrict__ part, float* __restrict__ loss_out) {
    __shared__ double s[16];
    const int tid = threadIdx.x;       // 1024 threads, one block
    double v = part[tid] + part[tid + 1024];
    for (int off = 32; off > 0; off >>= 1) v += __shfl_down(v, off, 64);
    if ((tid & 63) == 0) s[tid >> 6] = v;
    __syncthreads();
    if (tid == 0) {
        double t = 0.0;
        #pragma unroll
        for (int i = 0; i < 16; ++i) t += s[i];
        // loss = codebook_loss + 0.25*commitment = 1.25 * mean((z_q - z)^2)
        *loss_out = (float)(1.25 * t / (double)ZQ_ELEMS);
    }
}

extern "C" void kernel_launch(void* const* d_in, const int* in_sizes, int n_in,
                              void* d_out, int out_size, void* d_ws, size_t ws_size,
                              hipStream_t stream) {
    const float* z  = (const float*)d_in[0];
    const float* cb = (const float*)d_in[1];
    float* out  = (float*)d_out;
    float* zq   = out;                       // 8388608
    float* loss = out + ZQ_ELEMS;            // 1
    float* idx  = out + ZQ_ELEMS + 1;        // 131072
    char* ws = (char*)d_ws;
    double* part = (double*)ws;              // 2048 doubles

    if (ws_size >= WS_NEEDED) {
        float* Bsq = (float*)(ws + WS_BSQ_OFF);
        float* zt  = (float*)(ws + WS_ZT_OFF);
        vq_prep<<<NBLK, 256, 0, stream>>>(z, cb, zt, Bsq);
        vq_main<true><<<NBLK, 256, 0, stream>>>(zt, cb, Bsq, zq, idx, part);
    } else {
        vq_main<false><<<NBLK, 256, 0, stream>>>(z, cb, nullptr, zq, idx, part);
    }
    vq_finalize<<<1, 1024, 0, stream>>>(part, loss);
}

// Round 6
// 309.541 us; speedup vs baseline: 3.1158x; 1.0014x over previous
//
#include <hip/hip_runtime.h>

#define CDIM 64
#define KCODES 1024
#define ZQ_ELEMS (32 * 64 * 64 * 64)  // 8388608
#define NROWS 131072
#define FLT_BIG 3.402823466e38f
#define NBLK 2048                     // 131072 rows / 64 rows per block

// ws layout (fast path): [0,16KB) part | [16KB,20KB) Bsq | [32KB, +32MB) zt
#define WS_BSQ_OFF   16384
#define WS_ZT_OFF    32768
#define WS_NEEDED    (WS_ZT_OFF + (size_t)NROWS * CDIM * 4)

// numpy-exact: A,B = 8-acc pairwise sum of squares; M = sequential fma over c;
// d = fl(fl(A+B)-2M); argmin strict < ascending k.

__device__ __forceinline__ float pairwise_sq64(const float* v) {
    float r[8];
    #pragma unroll
    for (int j = 0; j < 8; ++j) r[j] = __fmul_rn(v[j], v[j]);
    #pragma unroll
    for (int m = 1; m < 8; ++m) {
        #pragma unroll
        for (int j = 0; j < 8; ++j)
            r[j] = __fadd_rn(r[j], __fmul_rn(v[8 * m + j], v[8 * m + j]));
    }
    return __fadd_rn(__fadd_rn(__fadd_rn(r[0], r[1]), __fadd_rn(r[2], r[3])),
                     __fadd_rn(__fadd_rn(r[4], r[5]), __fadd_rn(r[6], r[7])));
}

// ---------------- prep: transpose z -> zt (contig rows) + Bsq ----------------
__global__ __launch_bounds__(256) void vq_prep(const float* __restrict__ z,
                                               const float* __restrict__ cb,
                                               float* __restrict__ zt,
                                               float* __restrict__ Bsq) {
    __shared__ float tile[64][65];
    const int tid = threadIdx.x;
    const int blk = blockIdx.x;
    const int n0 = blk * 64;
    const int b = n0 >> 12;
    const int hw0 = n0 & 4095;
    const float* __restrict__ zb = z + ((size_t)b << 18) + hw0;

    const int lane_hw = tid & 63;
    const int cg = tid >> 6;
    #pragma unroll
    for (int it = 0; it < 16; ++it) {
        int c = cg * 16 + it;
        tile[lane_hw][c] = zb[((size_t)c << 12) + lane_hw];
    }
    __syncthreads();

    const int r = tid >> 2;
    const int cq = tid & 3;
    float4* __restrict__ zrow = (float4*)(zt + (size_t)(n0 + r) * CDIM);
    #pragma unroll
    for (int q = 0; q < 4; ++q) {
        int c0 = cq * 16 + q * 4;
        zrow[c0 >> 2] = make_float4(tile[r][c0], tile[r][c0 + 1],
                                    tile[r][c0 + 2], tile[r][c0 + 3]);
    }

    if (blk < 4) {
        int k = blk * 256 + tid;
        Bsq[k] = pairwise_sq64(cb + k * CDIM);
    }
}

// ---------------- main ----------------
#define PIN4(Zi) asm volatile("" : "+v"(Zi.x), "+v"(Zi.y), "+v"(Zi.z), "+v"(Zi.w));

#define LOADZ_STRIDED(i) \
    float4 Z##i = make_float4(zp[(4 * i + 0) << 12], zp[(4 * i + 1) << 12], \
                              zp[(4 * i + 2) << 12], zp[(4 * i + 3) << 12]); \
    PIN4(Z##i)

#define ASTEP(Za, Zb) \
    r0 = __fadd_rn(r0, __fmul_rn(Za.x, Za.x)); \
    r1 = __fadd_rn(r1, __fmul_rn(Za.y, Za.y)); \
    r2 = __fadd_rn(r2, __fmul_rn(Za.z, Za.z)); \
    r3 = __fadd_rn(r3, __fmul_rn(Za.w, Za.w)); \
    r4 = __fadd_rn(r4, __fmul_rn(Zb.x, Zb.x)); \
    r5 = __fadd_rn(r5, __fmul_rn(Zb.y, Zb.y)); \
    r6 = __fadd_rn(r6, __fmul_rn(Zb.z, Zb.z)); \
    r7 = __fadd_rn(r7, __fmul_rn(Zb.w, Zb.w));

// 8 codes x 4 dims = 32 FMAs; each m-chain strictly sequential in c
#define KSTEP8(Zq, q) \
    { \
        float4 e0 = C0[q], e1 = C1[q], e2 = C2[q], e3 = C3[q]; \
        float4 e4 = C4[q], e5 = C5[q], e6 = C6[q], e7 = C7[q]; \
        m0 = __fmaf_rn(Zq.x, e0.x, m0); m0 = __fmaf_rn(Zq.y, e0.y, m0); \
        m0 = __fmaf_rn(Zq.z, e0.z, m0); m0 = __fmaf_rn(Zq.w, e0.w, m0); \
        m1 = __fmaf_rn(Zq.x, e1.x, m1); m1 = __fmaf_rn(Zq.y, e1.y, m1); \
        m1 = __fmaf_rn(Zq.z, e1.z, m1); m1 = __fmaf_rn(Zq.w, e1.w, m1); \
        m2 = __fmaf_rn(Zq.x, e2.x, m2); m2 = __fmaf_rn(Zq.y, e2.y, m2); \
        m2 = __fmaf_rn(Zq.z, e2.z, m2); m2 = __fmaf_rn(Zq.w, e2.w, m2); \
        m3 = __fmaf_rn(Zq.x, e3.x, m3); m3 = __fmaf_rn(Zq.y, e3.y, m3); \
        m3 = __fmaf_rn(Zq.z, e3.z, m3); m3 = __fmaf_rn(Zq.w, e3.w, m3); \
        m4 = __fmaf_rn(Zq.x, e4.x, m4); m4 = __fmaf_rn(Zq.y, e4.y, m4); \
        m4 = __fmaf_rn(Zq.z, e4.z, m4); m4 = __fmaf_rn(Zq.w, e4.w, m4); \
        m5 = __fmaf_rn(Zq.x, e5.x, m5); m5 = __fmaf_rn(Zq.y, e5.y, m5); \
        m5 = __fmaf_rn(Zq.z, e5.z, m5); m5 = __fmaf_rn(Zq.w, e5.w, m5); \
        m6 = __fmaf_rn(Zq.x, e6.x, m6); m6 = __fmaf_rn(Zq.y, e6.y, m6); \
        m6 = __fmaf_rn(Zq.z, e6.z, m6); m6 = __fmaf_rn(Zq.w, e6.w, m6); \
        m7 = __fmaf_rn(Zq.x, e7.x, m7); m7 = __fmaf_rn(Zq.y, e7.y, m7); \
        m7 = __fmaf_rn(Zq.z, e7.z, m7); m7 = __fmaf_rn(Zq.w, e7.w, m7); \
    }

#define DBEST(j, mj, Bj) \
    { \
        float dd = __fsub_rn(__fadd_rn(A, Bj), __fadd_rn(mj, mj)); \
        if (dd < best) { best = dd; bi = k + j; } \
    }

#define LSTEP(i, Zi) \
    { \
        float4 qv = cq4[i]; \
        zo[(4 * i + 0) << 12] = qv.x; \
        zo[(4 * i + 1) << 12] = qv.y; \
        zo[(4 * i + 2) << 12] = qv.z; \
        zo[(4 * i + 3) << 12] = qv.w; \
        lsum = fmaf(qv.x - Zi.x, qv.x - Zi.x, lsum); \
        lsum = fmaf(qv.y - Zi.y, qv.y - Zi.y, lsum); \
        lsum = fmaf(qv.z - Zi.z, qv.z - Zi.z, lsum); \
        lsum = fmaf(qv.w - Zi.w, qv.w - Zi.w, lsum); \
    }

template <bool CONTIG>
__global__ __launch_bounds__(256, 2) void vq_main(const float* __restrict__ z,
                                                  const float* __restrict__ cb,
                                                  const float* __restrict__ Bsq,
                                                  float* __restrict__ zq_out,
                                                  float* __restrict__ idx_out,
                                                  double* __restrict__ part) {
    __shared__ float sB[KCODES];
    __shared__ float sD[256];
    __shared__ int sI[256];
    const int tid = threadIdx.x;

    if constexpr (CONTIG) {
        #pragma unroll
        for (int k = tid; k < KCODES; k += 256) sB[k] = Bsq[k];
    } else {
        for (int k = tid; k < KCODES; k += 256) sB[k] = pairwise_sq64(cb + k * CDIM);
    }
    __syncthreads();

    const int lane = tid & 63;                  // row within block
    const int kseg = tid >> 6;                  // wave -> k segment
    const int n = blockIdx.x * 64 + lane;       // row id
    const int b = n >> 12;
    const int hw = n & 4095;

    float4 Z0, Z1, Z2, Z3, Z4, Z5, Z6, Z7, Z8, Z9, Z10, Z11, Z12, Z13, Z14, Z15;
    if constexpr (CONTIG) {
        const float4* __restrict__ zr = (const float4*)(z + (size_t)n * CDIM);
        Z0 = zr[0];   PIN4(Z0)   Z1 = zr[1];   PIN4(Z1)
        Z2 = zr[2];   PIN4(Z2)   Z3 = zr[3];   PIN4(Z3)
        Z4 = zr[4];   PIN4(Z4)   Z5 = zr[5];   PIN4(Z5)
        Z6 = zr[6];   PIN4(Z6)   Z7 = zr[7];   PIN4(Z7)
        Z8 = zr[8];   PIN4(Z8)   Z9 = zr[9];   PIN4(Z9)
        Z10 = zr[10]; PIN4(Z10)  Z11 = zr[11]; PIN4(Z11)
        Z12 = zr[12]; PIN4(Z12)  Z13 = zr[13]; PIN4(Z13)
        Z14 = zr[14]; PIN4(Z14)  Z15 = zr[15]; PIN4(Z15)
    } else {
        const float* __restrict__ zp = z + ((size_t)b << 18) + hw;
        LOADZ_STRIDED(0)  LOADZ_STRIDED(1)  LOADZ_STRIDED(2)  LOADZ_STRIDED(3)
        LOADZ_STRIDED(4)  LOADZ_STRIDED(5)  LOADZ_STRIDED(6)  LOADZ_STRIDED(7)
        LOADZ_STRIDED(8)  LOADZ_STRIDED(9)  LOADZ_STRIDED(10) LOADZ_STRIDED(11)
        LOADZ_STRIDED(12) LOADZ_STRIDED(13) LOADZ_STRIDED(14) LOADZ_STRIDED(15)
    }

    // A, numpy 8-acc pairwise (elements 8m+j -> r[j])
    float r0 = __fmul_rn(Z0.x, Z0.x), r1 = __fmul_rn(Z0.y, Z0.y);
    float r2 = __fmul_rn(Z0.z, Z0.z), r3 = __fmul_rn(Z0.w, Z0.w);
    float r4 = __fmul_rn(Z1.x, Z1.x), r5 = __fmul_rn(Z1.y, Z1.y);
    float r6 = __fmul_rn(Z1.z, Z1.z), r7 = __fmul_rn(Z1.w, Z1.w);
    ASTEP(Z2, Z3)   ASTEP(Z4, Z5)   ASTEP(Z6, Z7)
    ASTEP(Z8, Z9)   ASTEP(Z10, Z11) ASTEP(Z12, Z13) ASTEP(Z14, Z15)
    const float A = __fadd_rn(__fadd_rn(__fadd_rn(r0, r1), __fadd_rn(r2, r3)),
                              __fadd_rn(__fadd_rn(r4, r5), __fadd_rn(r6, r7)));

    float best = FLT_BIG;
    int bi = 0;
    const int kbase = __builtin_amdgcn_readfirstlane(kseg << 8);

    for (int k = kbase; k < kbase + 256; k += 8) {
        const float4* __restrict__ C0 = (const float4*)(cb + (size_t)(k + 0) * CDIM);
        const float4* __restrict__ C1 = (const float4*)(cb + (size_t)(k + 1) * CDIM);
        const float4* __restrict__ C2 = (const float4*)(cb + (size_t)(k + 2) * CDIM);
        const float4* __restrict__ C3 = (const float4*)(cb + (size_t)(k + 3) * CDIM);
        const float4* __restrict__ C4 = (const float4*)(cb + (size_t)(k + 4) * CDIM);
        const float4* __restrict__ C5 = (const float4*)(cb + (size_t)(k + 5) * CDIM);
        const float4* __restrict__ C6 = (const float4*)(cb + (size_t)(k + 6) * CDIM);
        const float4* __restrict__ C7 = (const float4*)(cb + (size_t)(k + 7) * CDIM);
        float m0 = 0.f, m1 = 0.f, m2 = 0.f, m3 = 0.f;
        float m4 = 0.f, m5 = 0.f, m6 = 0.f, m7 = 0.f;
        KSTEP8(Z0, 0)   KSTEP8(Z1, 1)   KSTEP8(Z2, 2)   KSTEP8(Z3, 3)
        KSTEP8(Z4, 4)   KSTEP8(Z5, 5)   KSTEP8(Z6, 6)   KSTEP8(Z7, 7)
        KSTEP8(Z8, 8)   KSTEP8(Z9, 9)   KSTEP8(Z10, 10) KSTEP8(Z11, 11)
        KSTEP8(Z12, 12) KSTEP8(Z13, 13) KSTEP8(Z14, 14) KSTEP8(Z15, 15)

        float4 Ba = ((const float4*)sB)[(k >> 2) + 0];
        float4 Bb = ((const float4*)sB)[(k >> 2) + 1];
        DBEST(0, m0, Ba.x) DBEST(1, m1, Ba.y) DBEST(2, m2, Ba.z) DBEST(3, m3, Ba.w)
        DBEST(4, m4, Bb.x) DBEST(5, m5, Bb.y) DBEST(6, m6, Bb.z) DBEST(7, m7, Bb.w)
    }

    sD[tid] = best;
    sI[tid] = bi;
    __syncthreads();

    if (tid < 64) {
        float bd = sD[tid];
        int bk = sI[tid];
        #pragma unroll
        for (int s = 1; s < 4; ++s) {
            float d = sD[s * 64 + tid];
            int kk = sI[s * 64 + tid];
            if (d < bd) { bd = d; bk = kk; }
        }

        idx_out[n] = (float)bk;

        const float4* __restrict__ cq4 = (const float4*)(cb + (size_t)bk * CDIM);
        float* __restrict__ zo = zq_out + ((size_t)b << 18) + hw;
        float lsum = 0.f;
        LSTEP(0, Z0)   LSTEP(1, Z1)   LSTEP(2, Z2)   LSTEP(3, Z3)
        LSTEP(4, Z4)   LSTEP(5, Z5)   LSTEP(6, Z6)   LSTEP(7, Z7)
        LSTEP(8, Z8)   LSTEP(9, Z9)   LSTEP(10, Z10) LSTEP(11, Z11)
        LSTEP(12, Z12) LSTEP(13, Z13) LSTEP(14, Z14) LSTEP(15, Z15)

        double ls = (double)lsum;
        for (int off = 32; off > 0; off >>= 1) ls += __shfl_down(ls, off, 64);
        if (tid == 0) part[blockIdx.x] = ls;
    }
}

__global__ void vq_finalize(const double* __restrict__ part, float* __restrict__ loss_out) {
    __shared__ double s[16];
    const int tid = threadIdx.x;       // 1024 threads, one block
    double v = part[tid] + part[tid + 1024];
    for (int off = 32; off > 0; off >>= 1) v += __shfl_down(v, off, 64);
    if ((tid & 63) == 0) s[tid >> 6] = v;
    __syncthreads();
    if (tid == 0) {
        double t = 0.0;
        #pragma unroll
        for (int i = 0; i < 16; ++i) t += s[i];
        // loss = codebook_loss + 0.25*commitment = 1.25 * mean((z_q - z)^2)
        *loss_out = (float)(1.25 * t / (double)ZQ_ELEMS);
    }
}

extern "C" void kernel_launch(void* const* d_in, const int* in_sizes, int n_in,
                              void* d_out, int out_size, void* d_ws, size_t ws_size,
                              hipStream_t stream) {
    const float* z  = (const float*)d_in[0];
    const float* cb = (const float*)d_in[1];
    float* out  = (float*)d_out;
    float* zq   = out;                       // 8388608
    float* loss = out + ZQ_ELEMS;            // 1
    float* idx  = out + ZQ_ELEMS + 1;        // 131072
    char* ws = (char*)d_ws;
    double* part = (double*)ws;              // 2048 doubles

    if (ws_size >= WS_NEEDED) {
        float* Bsq = (float*)(ws + WS_BSQ_OFF);
        float* zt  = (float*)(ws + WS_ZT_OFF);
        vq_prep<<<NBLK, 256, 0, stream>>>(z, cb, zt, Bsq);
        vq_main<true><<<NBLK, 256, 0, stream>>>(zt, cb, Bsq, zq, idx, part);
    } else {
        vq_main<false><<<NBLK, 256, 0, stream>>>(z, cb, nullptr, zq, idx, part);
    }
    vq_finalize<<<1, 1024, 0, stream>>>(part, loss);
}